// Round 5
// baseline (362.822 us; speedup 1.0000x reference)
//
#include <hip/hip_runtime.h>

typedef unsigned short u16;
typedef unsigned int u32;
typedef short bf16x8 __attribute__((ext_vector_type(8)));
typedef float f32x4 __attribute__((ext_vector_type(4)));
typedef unsigned short u16x4 __attribute__((ext_vector_type(4)));
typedef unsigned short u16x8 __attribute__((ext_vector_type(8)));

__device__ __forceinline__ u16 f32_to_bf16(float f) {
    u32 u = __float_as_uint(f);
    u += 0x7FFFu + ((u >> 16) & 1u);
    return (u16)(u >> 16);
}
// truncating cast (p in [0,1], P-matrix only)
__device__ __forceinline__ short f32_to_bf16_trunc(float f) {
    return (short)(__float_as_uint(f) >> 16);
}

// async global->LDS, 16B per lane; lds pointer must be wave-uniform
__device__ __forceinline__ void gl_lds16(const u16* g, u16* l) {
    __builtin_amdgcn_global_load_lds(
        (const __attribute__((address_space(1))) u32*)g,
        (__attribute__((address_space(3))) u32*)l, 16, 0, 0);
}

// ---------------------------------------------------------------------------
// bulk fp32 -> bf16 cast
// ---------------------------------------------------------------------------
struct CastArgs {
    const float* src[7];
    u16* dst[7];
    int n4[7];
};

__global__ __launch_bounds__(256) void cast_kernel(CastArgs a) {
    const int y = blockIdx.y;
    const float* s = a.src[y];
    u16* d = a.dst[y];
    const int n4 = a.n4[y];
    for (int i = blockIdx.x * blockDim.x + threadIdx.x; i < n4; i += gridDim.x * blockDim.x) {
        f32x4 v = *(const f32x4*)&s[(size_t)i * 4];
        u16x4 o = { f32_to_bf16(v[0]), f32_to_bf16(v[1]), f32_to_bf16(v[2]), f32_to_bf16(v[3]) };
        *(u16x4*)&d[(size_t)i * 4] = o;
    }
}

#define GK 1024
#define GN 1024
#define GM 4096

// ---------------------------------------------------------------------------
// QKV projection GEMM + RoPE. 128x128 tile, BK=32, grid (32 m, 8 n, 3 z).
// z=0 Q normal layout (scaled 1/8), z=1 K tile layout KT[h][kb][kl][dk],
// z=2 V tile-transposed-permuted VT[h][kb][dv][kl'].
// Epilogues for z=0/1 use per-wave LDS transpose -> 16-B stores.
// ---------------------------------------------------------------------------
__global__ __launch_bounds__(256) void gemm_rope(
    const u16* __restrict__ A0, const u16* __restrict__ A1, const u16* __restrict__ A2,
    const u16* __restrict__ W0, const u16* __restrict__ W1, const u16* __restrict__ W2,
    u16* __restrict__ C0, u16* __restrict__ C1, u16* __restrict__ C2,
    const float* __restrict__ freqs)
{
    __shared__ u16 SM[8192];
    u16* As = SM;
    u16* Bs = SM + 4096;

    const int z = blockIdx.z;
    const u16* A = (z == 0) ? A0 : ((z == 1) ? A1 : A2);
    const u16* W = (z == 0) ? W0 : ((z == 1) ? W1 : W2);
    u16* Cb      = (z == 0) ? C0 : ((z == 1) ? C1 : C2);
    const float ascale = (z == 0) ? 0.125f : 1.0f;

    const int tid  = threadIdx.x;
    const int w    = tid >> 6;
    const int lane = tid & 63;
    const int quad = lane >> 4;
    const int l16  = lane & 15;
    const int m0 = blockIdx.x * 128;
    const int n0 = blockIdx.y * 128;
    const int wm = (w >> 1) * 64;
    const int wn = (w & 1) * 64;

    const int sr = tid >> 2;
    const int sc = (tid & 3) * 8;
    const size_t aoff0 = (size_t)(m0 + sr) * GK + sc;
    const size_t aoff1 = aoff0 + (size_t)64 * GK;
    const size_t boff0 = (size_t)(n0 + sr) * GK + sc;
    const size_t boff1 = boff0 + (size_t)64 * GK;
    u16* ldsA0 = &As[w * 512];
    u16* ldsA1 = &As[2048 + w * 512];
    u16* ldsB0 = &Bs[w * 512];
    u16* ldsB1 = &Bs[2048 + w * 512];

    f32x4 acc[4][4];
    for (int i = 0; i < 4; i++)
        for (int j = 0; j < 4; j++) acc[i][j] = 0.f;

    for (int k0 = 0; k0 < GK; k0 += 32) {
        gl_lds16(A + aoff0 + k0, ldsA0);
        gl_lds16(A + aoff1 + k0, ldsA1);
        gl_lds16(W + boff0 + k0, ldsB0);
        gl_lds16(W + boff1 + k0, ldsB1);
        __syncthreads();

        bf16x8 af[4], bfr[4];
        for (int t = 0; t < 4; t++) {
            af[t]  = *(const bf16x8*)&As[(wm + t * 16 + l16) * 32 + quad * 8];
            bfr[t] = *(const bf16x8*)&Bs[(wn + t * 16 + l16) * 32 + quad * 8];
        }
        for (int mt = 0; mt < 4; mt++)
            for (int nt = 0; nt < 4; nt++)
                acc[mt][nt] = __builtin_amdgcn_mfma_f32_16x16x32_bf16(
                    af[mt], bfr[nt], acc[mt][nt], 0, 0, 0);
        __syncthreads();
    }
    // after final barrier As/Bs are dead; per-wave scratch (wave-private)
    u16* tr = SM + w * 1152;  // 16 rows x 72 u16 (144 B rows, 16-B aligned)

    const int hh = (n0 + wn) >> 6;
    const size_t tb = (size_t)hh * 262144 + (size_t)((m0 + wm) >> 6) * 4096;

    if (z != 2) {
        for (int mt = 0; mt < 4; mt++) {
            // RoPE + scale + bf16 (values still in C-layout)
            #pragma unroll
            for (int r = 0; r < 4; r++) {
                int m = m0 + wm + mt * 16 + quad * 4 + r;
                float v0 = acc[mt][0][r];
                float v1 = acc[mt][1][r];
                float f0 = freqs[m * 32 + l16];
                float f1 = freqs[m * 32 + 16 + l16];
                float s0, c0, s1, c1;
                __sincosf(f0, &s0, &c0);
                __sincosf(f1, &s1, &c1);
                int row = quad * 4 + r;
                tr[row * 72 + l16]      = f32_to_bf16((v0 * c0 - v1 * s0) * ascale);
                tr[row * 72 + 16 + l16] = f32_to_bf16((v1 * c1 + v0 * s1) * ascale);
                tr[row * 72 + 32 + l16] = f32_to_bf16(acc[mt][2][r] * ascale);
                tr[row * 72 + 48 + l16] = f32_to_bf16(acc[mt][3][r] * ascale);
            }
            // wave-private transpose read: lane -> row l16, cols quad*16..+16
            u16x8 va = *(const u16x8*)&tr[l16 * 72 + quad * 16];
            u16x8 vb = *(const u16x8*)&tr[l16 * 72 + quad * 16 + 8];
            if (z == 0) {
                size_t base = (size_t)(m0 + wm + mt * 16 + l16) * GN + n0 + wn + quad * 16;
                *(u16x8*)&Cb[base]     = va;
                *(u16x8*)&Cb[base + 8] = vb;
            } else {
                size_t base = tb + (size_t)(mt * 16 + l16) * 64 + quad * 16;
                *(u16x8*)&Cb[base]     = va;
                *(u16x8*)&Cb[base + 8] = vb;
            }
        }
    } else {
        // V: VT[h][kb][dv][kl'], key permutation kappa baked into slot index
        for (int mt = 0; mt < 4; mt++) {
            float o0[4], o1[4];
            for (int r = 0; r < 4; r++) {
                int m = m0 + wm + mt * 16 + quad * 4 + r;
                float v0 = acc[mt][0][r];
                float v1 = acc[mt][1][r];
                float f0 = freqs[m * 32 + l16];
                float f1 = freqs[m * 32 + 16 + l16];
                float s0, c0, s1, c1;
                __sincosf(f0, &s0, &c0);
                __sincosf(f1, &s1, &c1);
                o0[r] = v0 * c0 - v1 * s0;
                o1[r] = v1 * c1 + v0 * s1;
            }
            const int sl = 32 * (mt >> 1) + 4 * (mt & 1) + 8 * quad;
            u16x4 u;
            u = { f32_to_bf16(o0[0]), f32_to_bf16(o0[1]), f32_to_bf16(o0[2]), f32_to_bf16(o0[3]) };
            *(u16x4*)&Cb[tb + (size_t)l16 * 64 + sl] = u;
            u = { f32_to_bf16(o1[0]), f32_to_bf16(o1[1]), f32_to_bf16(o1[2]), f32_to_bf16(o1[3]) };
            *(u16x4*)&Cb[tb + (size_t)(16 + l16) * 64 + sl] = u;
            u = { f32_to_bf16(acc[mt][2][0]), f32_to_bf16(acc[mt][2][1]),
                  f32_to_bf16(acc[mt][2][2]), f32_to_bf16(acc[mt][2][3]) };
            *(u16x4*)&Cb[tb + (size_t)(32 + l16) * 64 + sl] = u;
            u = { f32_to_bf16(acc[mt][3][0]), f32_to_bf16(acc[mt][3][1]),
                  f32_to_bf16(acc[mt][3][2]), f32_to_bf16(acc[mt][3][3]) };
            *(u16x4*)&Cb[tb + (size_t)(48 + l16) * 64 + sl] = u;
        }
    }
}

// ---------------------------------------------------------------------------
// Output projection GEMM, split-K x2. 128x128 tile, grid (32, 8, 2).
// z selects K half [z*512, z*512+512) and the fp32 partial buffer.
// Epilogue: per-wave LDS transpose -> dwordx4 stores.
// ---------------------------------------------------------------------------
__global__ __launch_bounds__(256) void gemm_out(
    const u16* __restrict__ A, const u16* __restrict__ W,
    float* __restrict__ O0, float* __restrict__ O1)
{
    __shared__ u16 SM[8704];  // 17408 B: staging 16 KB / epilogue fp32 scratch 17.4 KB
    u16* As = SM;
    u16* Bs = SM + 4096;

    const int z = blockIdx.z;
    float* C = z ? O1 : O0;
    const int kbeg = z * 512;

    const int tid  = threadIdx.x;
    const int w    = tid >> 6;
    const int lane = tid & 63;
    const int quad = lane >> 4;
    const int l16  = lane & 15;
    const int m0 = blockIdx.x * 128;
    const int n0 = blockIdx.y * 128;
    const int wm = (w >> 1) * 64;
    const int wn = (w & 1) * 64;

    const int sr = tid >> 2;
    const int sc = (tid & 3) * 8;
    const size_t aoff0 = (size_t)(m0 + sr) * GK + kbeg + sc;
    const size_t aoff1 = aoff0 + (size_t)64 * GK;
    const size_t boff0 = (size_t)(n0 + sr) * GK + kbeg + sc;
    const size_t boff1 = boff0 + (size_t)64 * GK;
    u16* ldsA0 = &As[w * 512];
    u16* ldsA1 = &As[2048 + w * 512];
    u16* ldsB0 = &Bs[w * 512];
    u16* ldsB1 = &Bs[2048 + w * 512];

    f32x4 acc[4][4];
    for (int i = 0; i < 4; i++)
        for (int j = 0; j < 4; j++) acc[i][j] = 0.f;

    for (int k0 = 0; k0 < 512; k0 += 32) {
        gl_lds16(A + aoff0 + k0, ldsA0);
        gl_lds16(A + aoff1 + k0, ldsA1);
        gl_lds16(W + boff0 + k0, ldsB0);
        gl_lds16(W + boff1 + k0, ldsB1);
        __syncthreads();

        bf16x8 af[4], bfr[4];
        for (int t = 0; t < 4; t++) {
            af[t]  = *(const bf16x8*)&As[(wm + t * 16 + l16) * 32 + quad * 8];
            bfr[t] = *(const bf16x8*)&Bs[(wn + t * 16 + l16) * 32 + quad * 8];
        }
        for (int mt = 0; mt < 4; mt++)
            for (int nt = 0; nt < 4; nt++)
                acc[mt][nt] = __builtin_amdgcn_mfma_f32_16x16x32_bf16(
                    af[mt], bfr[nt], acc[mt][nt], 0, 0, 0);
        __syncthreads();
    }

    // per-wave fp32 transpose scratch: 16 rows x 68 floats (16-B aligned rows)
    float* tr = (float*)SM + w * 1088;
    for (int mt = 0; mt < 4; mt++) {
        #pragma unroll
        for (int nt = 0; nt < 4; nt++)
            #pragma unroll
            for (int r = 0; r < 4; r++)
                tr[(quad * 4 + r) * 68 + nt * 16 + l16] = acc[mt][nt][r];
        size_t base = (size_t)(m0 + wm + mt * 16 + l16) * GN + n0 + wn + quad * 16;
        #pragma unroll
        for (int c = 0; c < 4; c++) {
            f32x4 v = *(const f32x4*)&tr[l16 * 68 + quad * 16 + c * 4];
            *(f32x4*)&C[base + c * 4] = v;
        }
    }
}

__global__ __launch_bounds__(256) void add_kernel(
    const float* __restrict__ O0, const float* __restrict__ O1, float* __restrict__ out)
{
    int i = blockIdx.x * 256 + threadIdx.x;
    f32x4 a = *(const f32x4*)&O0[(size_t)i * 4];
    f32x4 b = *(const f32x4*)&O1[(size_t)i * 4];
    f32x4 c = a + b;
    *(f32x4*)&out[(size_t)i * 4] = c;
}

// ---------------------------------------------------------------------------
// Flash attention, causal. Grid 1024 x 256 thr (4 waves).
// Block = (head h, pair {p, 127-p}); granule = 32 q-rows. Waves 0,1 -> granule
// p with key halves [0,nt/2) / [nt/2,nt); waves 2,3 -> granule 127-p likewise.
// Fixed-max softmax (exp(s-16)) makes O,l pure sums -> key-split partials
// combine with one LDS roundtrip + one barrier. K double-buffered in regs.
// S^T = K*Q^T; P repacked register-only into PV B-operand (V pre-permuted).
// ---------------------------------------------------------------------------
__global__ __launch_bounds__(256) void attn_kernel(
    const u16* __restrict__ Qb, const u16* __restrict__ KT,
    const u16* __restrict__ VTg, u16* __restrict__ valsb)
{
    // Part[g2][lane*35 + j]: j 0..31 = o partial, 32/33 = lsum[qt].
    // After the barrier, even wave g2 reuses Part[g2] as Ow[32 rows x 68].
    __shared__ float Part[2][64 * 35];

    const int tid  = threadIdx.x;
    const int w    = tid >> 6;
    const int lane = tid & 63;
    const int quad = lane >> 4;
    const int l16  = lane & 15;
    const int HD = 1024;

    const int id = blockIdx.x;
    const int h  = (id & 7) * 2 + ((id >> 3) & 1);
    const int p  = id >> 4;                    // 0..63
    const int g  = (w < 2) ? p : (127 - p);    // granule: q rows [32g, 32g+32)
    const int nt = (g >> 1) + 1;               // key tiles for this granule
    const int kb_last = nt - 1;
    const int klo = (w & 1) ? (nt >> 1) : 0;
    const int khi = (w & 1) ? nt : (nt >> 1);
    const int qoff = (g & 1) * 32;

    const u16* kt = KT  + (size_t)h * 262144;
    const u16* vt = VTg + (size_t)h * 262144;

    bf16x8 bq[2][2];
    #pragma unroll
    for (int qt = 0; qt < 2; qt++)
        #pragma unroll
        for (int ks = 0; ks < 2; ks++)
            bq[qt][ks] = *(const bf16x8*)&Qb[(size_t)(g * 32 + qt * 16 + l16) * HD
                                             + h * 64 + ks * 32 + quad * 8];

    f32x4 o[2][4];
    #pragma unroll
    for (int qt = 0; qt < 2; qt++)
        #pragma unroll
        for (int nv = 0; nv < 4; nv++) o[qt][nv] = 0.f;
    float lsum[2] = { 0.f, 0.f };

    bf16x8 akA[8], akB[8];

    auto loadK = [&](bf16x8* ak, int kb) {
        const u16* base = kt + kb * 4096;
        #pragma unroll
        for (int nt2 = 0; nt2 < 4; nt2++) {
            ak[nt2 * 2]     = *(const bf16x8*)&base[(nt2 * 16 + l16) * 64 + quad * 8];
            ak[nt2 * 2 + 1] = *(const bf16x8*)&base[(nt2 * 16 + l16) * 64 + 32 + quad * 8];
        }
    };

    auto body = [&](const bf16x8* ak, int kb) {
        bf16x8 av[8];
        const u16* vb = vt + kb * 4096;
        #pragma unroll
        for (int nv = 0; nv < 4; nv++) {
            av[nv * 2]     = *(const bf16x8*)&vb[(nv * 16 + l16) * 64 + quad * 8];
            av[nv * 2 + 1] = *(const bf16x8*)&vb[(nv * 16 + l16) * 64 + 32 + quad * 8];
        }

        f32x4 s[2][4];
        #pragma unroll
        for (int qt = 0; qt < 2; qt++)
            #pragma unroll
            for (int nt2 = 0; nt2 < 4; nt2++) {
                f32x4 z4 = { 0.f, 0.f, 0.f, 0.f };
                s[qt][nt2] = __builtin_amdgcn_mfma_f32_16x16x32_bf16(
                    ak[nt2 * 2], bq[qt][0], z4, 0, 0, 0);
                s[qt][nt2] = __builtin_amdgcn_mfma_f32_16x16x32_bf16(
                    ak[nt2 * 2 + 1], bq[qt][1], s[qt][nt2], 0, 0, 0);
            }

        if (kb == kb_last) {  // diagonal tile (always owned by the odd wave)
            #pragma unroll
            for (int qt = 0; qt < 2; qt++) {
                const int ql = qoff + qt * 16 + l16;
                #pragma unroll
                for (int nt2 = 0; nt2 < 4; nt2++)
                    #pragma unroll
                    for (int r = 0; r < 4; r++)
                        if (nt2 * 16 + quad * 4 + r > ql) s[qt][nt2][r] = -1e30f;
            }
        }

        #pragma unroll
        for (int qt = 0; qt < 2; qt++) {
            float ls = 0.f;
            #pragma unroll
            for (int nt2 = 0; nt2 < 4; nt2++)
                #pragma unroll
                for (int r = 0; r < 4; r++) {
                    float pe = __expf(s[qt][nt2][r] - 16.f);
                    s[qt][nt2][r] = pe;
                    ls += pe;
                }
            lsum[qt] += ls;

            bf16x8 bp0 = { f32_to_bf16_trunc(s[qt][0][0]), f32_to_bf16_trunc(s[qt][0][1]),
                           f32_to_bf16_trunc(s[qt][0][2]), f32_to_bf16_trunc(s[qt][0][3]),
                           f32_to_bf16_trunc(s[qt][1][0]), f32_to_bf16_trunc(s[qt][1][1]),
                           f32_to_bf16_trunc(s[qt][1][2]), f32_to_bf16_trunc(s[qt][1][3]) };
            bf16x8 bp1 = { f32_to_bf16_trunc(s[qt][2][0]), f32_to_bf16_trunc(s[qt][2][1]),
                           f32_to_bf16_trunc(s[qt][2][2]), f32_to_bf16_trunc(s[qt][2][3]),
                           f32_to_bf16_trunc(s[qt][3][0]), f32_to_bf16_trunc(s[qt][3][1]),
                           f32_to_bf16_trunc(s[qt][3][2]), f32_to_bf16_trunc(s[qt][3][3]) };
            #pragma unroll
            for (int nv = 0; nv < 4; nv++) {
                o[qt][nv] = __builtin_amdgcn_mfma_f32_16x16x32_bf16(
                    av[nv * 2], bp0, o[qt][nv], 0, 0, 0);
                o[qt][nv] = __builtin_amdgcn_mfma_f32_16x16x32_bf16(
                    av[nv * 2 + 1], bp1, o[qt][nv], 0, 0, 0);
            }
        }
    };

    if (klo < khi) {
        loadK(akA, klo);
        int kb = klo;
        while (true) {
            if (kb + 1 < khi) loadK(akB, kb + 1);
            body(akA, kb);
            kb++;
            if (kb >= khi) break;
            if (kb + 1 < khi) loadK(akA, kb + 1);
            body(akB, kb);
            kb++;
            if (kb >= khi) break;
        }
    }

    // odd waves publish partials
    if (w & 1) {
        float* P = Part[w >> 1];
        #pragma unroll
        for (int qt = 0; qt < 2; qt++)
            #pragma unroll
            for (int nv = 0; nv < 4; nv++)
                #pragma unroll
                for (int r = 0; r < 4; r++)
                    P[lane * 35 + qt * 16 + nv * 4 + r] = o[qt][nv][r];
        P[lane * 35 + 32] = lsum[0];
        P[lane * 35 + 33] = lsum[1];
    }
    __syncthreads();

    // even waves combine + finalize
    if (!(w & 1)) {
        float* P = Part[w >> 1];
        float linv[2];
        #pragma unroll
        for (int qt = 0; qt < 2; qt++) {
            float l = lsum[qt] + P[lane * 35 + 32 + qt];
            l += __shfl_xor(l, 16);
            l += __shfl_xor(l, 32);
            linv[qt] = 1.f / l;
        }
        float oc[2][4][4];
        #pragma unroll
        for (int qt = 0; qt < 2; qt++)
            #pragma unroll
            for (int nv = 0; nv < 4; nv++)
                #pragma unroll
                for (int r = 0; r < 4; r++)
                    oc[qt][nv][r] = (o[qt][nv][r] + P[lane * 35 + qt * 16 + nv * 4 + r]) * linv[qt];
        // reuse region as Ow[32 rows x 68] (all reads above done, lockstep wave)
        float* Ow = P;
        #pragma unroll
        for (int qt = 0; qt < 2; qt++)
            #pragma unroll
            for (int nv = 0; nv < 4; nv++)
                #pragma unroll
                for (int r = 0; r < 4; r++)
                    Ow[(qt * 16 + l16) * 68 + nv * 16 + quad * 4 + r] = oc[qt][nv][r];
        #pragma unroll
        for (int i = 0; i < 8; i++) {
            int row = i * 4 + quad;   // q row within granule [0,32)
            f32x4 vv = *(const f32x4*)&Ow[row * 68 + l16 * 4];
            u16x4 u = { f32_to_bf16(vv[0]), f32_to_bf16(vv[1]), f32_to_bf16(vv[2]), f32_to_bf16(vv[3]) };
            *(u16x4*)&valsb[(size_t)(g * 32 + row) * HD + h * 64 + l16 * 4] = u;
        }
    }
}

// ---------------------------------------------------------------------------
// ws layout (u16 idx): qc 0 | kc 4M | vc 8M | wqc 12M | wkc 13M | wvc 14M |
// woc 15M | Qb 16M | KT 20M | VT 24M | (O1 fp32 over VT.. 25165824, 16 MB)
// O0 fp32 over Qb+KT (16777216, 16 MB). valsb reuses qc. Total 64 MiB.
// ---------------------------------------------------------------------------
extern "C" void kernel_launch(void* const* d_in, const int* in_sizes, int n_in,
                              void* d_out, int out_size, void* d_ws, size_t ws_size,
                              hipStream_t stream) {
    const float* q     = (const float*)d_in[0];
    const float* k     = (const float*)d_in[1];
    const float* v     = (const float*)d_in[2];
    const float* freqs = (const float*)d_in[4];
    const float* wq    = (const float*)d_in[5];
    const float* wk    = (const float*)d_in[6];
    const float* wv    = (const float*)d_in[7];
    const float* wo    = (const float*)d_in[8];

    u16* B = (u16*)d_ws;
    u16* qc  = B;
    u16* kc  = B + (size_t)4194304;
    u16* vc  = B + (size_t)8388608;
    u16* wqc = B + (size_t)12582912;
    u16* wkc = B + (size_t)13631488;
    u16* wvc = B + (size_t)14680064;
    u16* woc = B + (size_t)15728640;
    u16* Qb  = B + (size_t)16777216;
    u16* KT  = B + (size_t)20971520;
    u16* VT  = B + (size_t)25165824;
    u16* valsb = qc;                      // dead after qkv GEMM reads it
    float* O0 = (float*)(B + (size_t)16777216);  // over Qb+KT (dead after attn)
    float* O1 = (float*)(B + (size_t)25165824);  // over VT+8MB (dead after attn)

    CastArgs ca;
    ca.src[0] = q;  ca.dst[0] = qc;  ca.n4[0] = 1048576;
    ca.src[1] = k;  ca.dst[1] = kc;  ca.n4[1] = 1048576;
    ca.src[2] = v;  ca.dst[2] = vc;  ca.n4[2] = 1048576;
    ca.src[3] = wq; ca.dst[3] = wqc; ca.n4[3] = 262144;
    ca.src[4] = wk; ca.dst[4] = wkc; ca.n4[4] = 262144;
    ca.src[5] = wv; ca.dst[5] = wvc; ca.n4[5] = 262144;
    ca.src[6] = wo; ca.dst[6] = woc; ca.n4[6] = 262144;
    cast_kernel<<<dim3(1024, 7), 256, 0, stream>>>(ca);

    gemm_rope<<<dim3(32, 8, 3), 256, 0, stream>>>(
        qc, kc, vc, wqc, wkc, wvc, Qb, KT, VT, freqs);

    attn_kernel<<<dim3(1024), 256, 0, stream>>>(Qb, KT, VT, valsb);

    gemm_out<<<dim3(32, 8, 2), 256, 0, stream>>>(valsb, woc, O0, O1);

    add_kernel<<<dim3(4096), 256, 0, stream>>>(O0, O1, (float*)d_out);
}

// Round 6
// 286.437 us; speedup vs baseline: 1.2667x; 1.2667x over previous
//
#include <hip/hip_runtime.h>

typedef unsigned short u16;
typedef unsigned int u32;
typedef short bf16x8 __attribute__((ext_vector_type(8)));
typedef float f32x4 __attribute__((ext_vector_type(4)));
typedef unsigned short u16x4 __attribute__((ext_vector_type(4)));
typedef unsigned short u16x8 __attribute__((ext_vector_type(8)));

__device__ __forceinline__ u16 f32_to_bf16(float f) {
    u32 u = __float_as_uint(f);
    u += 0x7FFFu + ((u >> 16) & 1u);
    return (u16)(u >> 16);
}
// truncating cast (p in [0,1], P-matrix only)
__device__ __forceinline__ short f32_to_bf16_trunc(float f) {
    return (short)(__float_as_uint(f) >> 16);
}

// async global->LDS, 16B per lane; lds pointer must be wave-uniform
__device__ __forceinline__ void gl_lds16(const u16* g, u16* l) {
    __builtin_amdgcn_global_load_lds(
        (const __attribute__((address_space(1))) u32*)g,
        (__attribute__((address_space(3))) u32*)l, 16, 0, 0);
}

// ---------------------------------------------------------------------------
// bulk fp32 -> bf16 cast
// ---------------------------------------------------------------------------
struct CastArgs {
    const float* src[7];
    u16* dst[7];
    int n4[7];
};

__global__ __launch_bounds__(256) void cast_kernel(CastArgs a) {
    const int y = blockIdx.y;
    const float* s = a.src[y];
    u16* d = a.dst[y];
    const int n4 = a.n4[y];
    for (int i = blockIdx.x * blockDim.x + threadIdx.x; i < n4; i += gridDim.x * blockDim.x) {
        f32x4 v = *(const f32x4*)&s[(size_t)i * 4];
        u16x4 o = { f32_to_bf16(v[0]), f32_to_bf16(v[1]), f32_to_bf16(v[2]), f32_to_bf16(v[3]) };
        *(u16x4*)&d[(size_t)i * 4] = o;
    }
}

#define GK 1024
#define GN 1024
#define GM 4096

// ---------------------------------------------------------------------------
// QKV projection GEMM + RoPE. 128x128 tile, BK=32, grid (32 m, 8 n, 3 z).
// z=0 Q: normal [t][HD] bf16, scaled 1/8.
// z=1 K: KT[h][kb][ks][kl][32]   (dk split in halves ks -> 64 B LDS rows)
// z=2 V: VT[h][kb][ks][dv][32']  (key halves; kappa permutation in slot idx)
// ---------------------------------------------------------------------------
__global__ __launch_bounds__(256) void gemm_rope(
    const u16* __restrict__ A0, const u16* __restrict__ A1, const u16* __restrict__ A2,
    const u16* __restrict__ W0, const u16* __restrict__ W1, const u16* __restrict__ W2,
    u16* __restrict__ C0, u16* __restrict__ C1, u16* __restrict__ C2,
    const float* __restrict__ freqs)
{
    __shared__ u16 SM[8192];
    u16* As = SM;
    u16* Bs = SM + 4096;

    const int z = blockIdx.z;
    const u16* A = (z == 0) ? A0 : ((z == 1) ? A1 : A2);
    const u16* W = (z == 0) ? W0 : ((z == 1) ? W1 : W2);
    u16* Cb      = (z == 0) ? C0 : ((z == 1) ? C1 : C2);
    const float ascale = (z == 0) ? 0.125f : 1.0f;

    const int tid  = threadIdx.x;
    const int w    = tid >> 6;
    const int lane = tid & 63;
    const int quad = lane >> 4;
    const int l16  = lane & 15;
    const int m0 = blockIdx.x * 128;
    const int n0 = blockIdx.y * 128;
    const int wm = (w >> 1) * 64;
    const int wn = (w & 1) * 64;

    const int sr = tid >> 2;
    const int sc = (tid & 3) * 8;
    const size_t aoff0 = (size_t)(m0 + sr) * GK + sc;
    const size_t aoff1 = aoff0 + (size_t)64 * GK;
    const size_t boff0 = (size_t)(n0 + sr) * GK + sc;
    const size_t boff1 = boff0 + (size_t)64 * GK;
    u16* ldsA0 = &As[w * 512];
    u16* ldsA1 = &As[2048 + w * 512];
    u16* ldsB0 = &Bs[w * 512];
    u16* ldsB1 = &Bs[2048 + w * 512];

    f32x4 acc[4][4];
    for (int i = 0; i < 4; i++)
        for (int j = 0; j < 4; j++) acc[i][j] = 0.f;

    for (int k0 = 0; k0 < GK; k0 += 32) {
        gl_lds16(A + aoff0 + k0, ldsA0);
        gl_lds16(A + aoff1 + k0, ldsA1);
        gl_lds16(W + boff0 + k0, ldsB0);
        gl_lds16(W + boff1 + k0, ldsB1);
        __syncthreads();

        bf16x8 af[4], bfr[4];
        for (int t = 0; t < 4; t++) {
            af[t]  = *(const bf16x8*)&As[(wm + t * 16 + l16) * 32 + quad * 8];
            bfr[t] = *(const bf16x8*)&Bs[(wn + t * 16 + l16) * 32 + quad * 8];
        }
        for (int mt = 0; mt < 4; mt++)
            for (int nt = 0; nt < 4; nt++)
                acc[mt][nt] = __builtin_amdgcn_mfma_f32_16x16x32_bf16(
                    af[mt], bfr[nt], acc[mt][nt], 0, 0, 0);
        __syncthreads();
    }
    // after final barrier As/Bs are dead; per-wave scratch (wave-private)
    u16* tr = SM + w * 1152;  // 16 rows x 72 u16

    const int hh = (n0 + wn) >> 6;
    const size_t tb = (size_t)hh * 262144 + (size_t)((m0 + wm) >> 6) * 4096;

    if (z != 2) {
        for (int mt = 0; mt < 4; mt++) {
            #pragma unroll
            for (int r = 0; r < 4; r++) {
                int m = m0 + wm + mt * 16 + quad * 4 + r;
                float v0 = acc[mt][0][r];
                float v1 = acc[mt][1][r];
                float f0 = freqs[m * 32 + l16];
                float f1 = freqs[m * 32 + 16 + l16];
                float s0, c0, s1, c1;
                __sincosf(f0, &s0, &c0);
                __sincosf(f1, &s1, &c1);
                int row = quad * 4 + r;
                tr[row * 72 + l16]      = f32_to_bf16((v0 * c0 - v1 * s0) * ascale);
                tr[row * 72 + 16 + l16] = f32_to_bf16((v1 * c1 + v0 * s1) * ascale);
                tr[row * 72 + 32 + l16] = f32_to_bf16(acc[mt][2][r] * ascale);
                tr[row * 72 + 48 + l16] = f32_to_bf16(acc[mt][3][r] * ascale);
            }
            // wave-private transpose read: lane -> row l16, cols quad*16..+16
            u16x8 va = *(const u16x8*)&tr[l16 * 72 + quad * 16];
            u16x8 vb = *(const u16x8*)&tr[l16 * 72 + quad * 16 + 8];
            if (z == 0) {
                size_t base = (size_t)(m0 + wm + mt * 16 + l16) * GN + n0 + wn + quad * 16;
                *(u16x8*)&Cb[base]     = va;
                *(u16x8*)&Cb[base + 8] = vb;
            } else {
                // K half-split: dk = quad*16 + c -> half ks = quad>>1, within = (quad&1)*16 + c
                size_t base = tb + (size_t)(quad >> 1) * 2048
                            + (size_t)(mt * 16 + l16) * 32 + (quad & 1) * 16;
                *(u16x8*)&Cb[base]     = va;
                *(u16x8*)&Cb[base + 8] = vb;
            }
        }
    } else {
        // V: VT[h][kb][ks][dv][32'], kappa within each 32-key half
        for (int mt = 0; mt < 4; mt++) {
            float o0[4], o1[4];
            for (int r = 0; r < 4; r++) {
                int m = m0 + wm + mt * 16 + quad * 4 + r;
                float v0 = acc[mt][0][r];
                float v1 = acc[mt][1][r];
                float f0 = freqs[m * 32 + l16];
                float f1 = freqs[m * 32 + 16 + l16];
                float s0, c0, s1, c1;
                __sincosf(f0, &s0, &c0);
                __sincosf(f1, &s1, &c1);
                o0[r] = v0 * c0 - v1 * s0;
                o1[r] = v1 * c1 + v0 * s1;
            }
            const int ks = mt >> 1;                       // key half
            const int sl = 4 * (mt & 1) + 8 * quad;       // slot within half (r adds 0..3)
            const size_t hb = tb + (size_t)ks * 2048 + sl;
            u16x4 u;
            u = { f32_to_bf16(o0[0]), f32_to_bf16(o0[1]), f32_to_bf16(o0[2]), f32_to_bf16(o0[3]) };
            *(u16x4*)&Cb[hb + (size_t)l16 * 32] = u;
            u = { f32_to_bf16(o1[0]), f32_to_bf16(o1[1]), f32_to_bf16(o1[2]), f32_to_bf16(o1[3]) };
            *(u16x4*)&Cb[hb + (size_t)(16 + l16) * 32] = u;
            u = { f32_to_bf16(acc[mt][2][0]), f32_to_bf16(acc[mt][2][1]),
                  f32_to_bf16(acc[mt][2][2]), f32_to_bf16(acc[mt][2][3]) };
            *(u16x4*)&Cb[hb + (size_t)(32 + l16) * 32] = u;
            u = { f32_to_bf16(acc[mt][3][0]), f32_to_bf16(acc[mt][3][1]),
                  f32_to_bf16(acc[mt][3][2]), f32_to_bf16(acc[mt][3][3]) };
            *(u16x4*)&Cb[hb + (size_t)(48 + l16) * 32] = u;
        }
    }
}

// ---------------------------------------------------------------------------
// Output projection GEMM, split-K x2. 128x128 tile, grid (32, 8, 2).
// ---------------------------------------------------------------------------
__global__ __launch_bounds__(256) void gemm_out(
    const u16* __restrict__ A, const u16* __restrict__ W,
    float* __restrict__ O0, float* __restrict__ O1)
{
    __shared__ u16 SM[8704];
    u16* As = SM;
    u16* Bs = SM + 4096;

    const int z = blockIdx.z;
    float* C = z ? O1 : O0;
    const int kbeg = z * 512;

    const int tid  = threadIdx.x;
    const int w    = tid >> 6;
    const int lane = tid & 63;
    const int quad = lane >> 4;
    const int l16  = lane & 15;
    const int m0 = blockIdx.x * 128;
    const int n0 = blockIdx.y * 128;
    const int wm = (w >> 1) * 64;
    const int wn = (w & 1) * 64;

    const int sr = tid >> 2;
    const int sc = (tid & 3) * 8;
    const size_t aoff0 = (size_t)(m0 + sr) * GK + kbeg + sc;
    const size_t aoff1 = aoff0 + (size_t)64 * GK;
    const size_t boff0 = (size_t)(n0 + sr) * GK + kbeg + sc;
    const size_t boff1 = boff0 + (size_t)64 * GK;
    u16* ldsA0 = &As[w * 512];
    u16* ldsA1 = &As[2048 + w * 512];
    u16* ldsB0 = &Bs[w * 512];
    u16* ldsB1 = &Bs[2048 + w * 512];

    f32x4 acc[4][4];
    for (int i = 0; i < 4; i++)
        for (int j = 0; j < 4; j++) acc[i][j] = 0.f;

    for (int k0 = 0; k0 < 512; k0 += 32) {
        gl_lds16(A + aoff0 + k0, ldsA0);
        gl_lds16(A + aoff1 + k0, ldsA1);
        gl_lds16(W + boff0 + k0, ldsB0);
        gl_lds16(W + boff1 + k0, ldsB1);
        __syncthreads();

        bf16x8 af[4], bfr[4];
        for (int t = 0; t < 4; t++) {
            af[t]  = *(const bf16x8*)&As[(wm + t * 16 + l16) * 32 + quad * 8];
            bfr[t] = *(const bf16x8*)&Bs[(wn + t * 16 + l16) * 32 + quad * 8];
        }
        for (int mt = 0; mt < 4; mt++)
            for (int nt = 0; nt < 4; nt++)
                acc[mt][nt] = __builtin_amdgcn_mfma_f32_16x16x32_bf16(
                    af[mt], bfr[nt], acc[mt][nt], 0, 0, 0);
        __syncthreads();
    }

    float* tr = (float*)SM + w * 1088;
    for (int mt = 0; mt < 4; mt++) {
        #pragma unroll
        for (int nt = 0; nt < 4; nt++)
            #pragma unroll
            for (int r = 0; r < 4; r++)
                tr[(quad * 4 + r) * 68 + nt * 16 + l16] = acc[mt][nt][r];
        size_t base = (size_t)(m0 + wm + mt * 16 + l16) * GN + n0 + wn + quad * 16;
        #pragma unroll
        for (int c = 0; c < 4; c++) {
            f32x4 v = *(const f32x4*)&tr[l16 * 68 + quad * 16 + c * 4];
            *(f32x4*)&C[base + c * 4] = v;
        }
    }
}

__global__ __launch_bounds__(256) void add_kernel(
    const float* __restrict__ O0, const float* __restrict__ O1, float* __restrict__ out)
{
    int i = blockIdx.x * 256 + threadIdx.x;
    f32x4 a = *(const f32x4*)&O0[(size_t)i * 4];
    f32x4 b = *(const f32x4*)&O1[(size_t)i * 4];
    f32x4 c = a + b;
    *(f32x4*)&out[(size_t)i * 4] = c;
}

// ---------------------------------------------------------------------------
// Flash attention, causal. Grid 512 x 256 thr (4 waves).
// Block = (head h, q-tile pair {p, 63-p}) processed sequentially -> 65 key-
// tile iterations per block, perfectly balanced, 2 blocks/CU fully resident.
// Wave w owns q rows [qb*64 + 16w, +16). K/V tiles staged once per block via
// async global_load_lds into a 32 KB LDS double buffer; DMA for kb+1 issued
// right after the top-of-loop barrier -> overlaps the whole compute of kb.
// One barrier per iteration. K/V LDS layout = 64 B rows (half-split) so
// ds_read_b128 frags hit the m97 2-bank-group pattern (no big conflicts).
// Fixed-max softmax (exp(s-16)); P repacked register-only into PV B-operand
// (V pre-permuted per-32-half by gemm_rope).
// ---------------------------------------------------------------------------
__global__ __launch_bounds__(256) void attn_kernel(
    const u16* __restrict__ Qb, const u16* __restrict__ KT,
    const u16* __restrict__ VTg, u16* __restrict__ valsb)
{
    __shared__ u16 KV[2][8192];     // [buf][ K 4096 | V 4096 ]
    __shared__ float Ow[4][16 * 68];

    const int tid  = threadIdx.x;
    const int w    = tid >> 6;
    const int lane = tid & 63;
    const int quad = lane >> 4;
    const int l16  = lane & 15;
    const int HD = 1024;

    const int id = blockIdx.x;
    const int h  = (id & 7) * 2 + ((id >> 3) & 1);
    const int p  = id >> 4;                    // 0..31

    const u16* kt = KT  + (size_t)h * 262144;
    const u16* vt = VTg + (size_t)h * 262144;

    for (int gi = 0; gi < 2; gi++) {
        const int qb = gi ? (63 - p) : p;

        // Q B-frags for this wave's 16 q rows
        const size_t qrow = (size_t)(qb * 64 + w * 16 + l16);
        bf16x8 bq0 = *(const bf16x8*)&Qb[qrow * HD + h * 64 + quad * 8];
        bf16x8 bq1 = *(const bf16x8*)&Qb[qrow * HD + h * 64 + 32 + quad * 8];

        f32x4 o[4];
        #pragma unroll
        for (int i = 0; i < 4; i++) o[i] = 0.f;
        float lsum = 0.f;
        const int q_local = w * 16 + l16;

        // ensure no wave is still reading KV from the previous phase
        __syncthreads();
        // prologue DMA: tile 0 -> buf 0
        {
            const u16* ksrc = kt;  const u16* vsrc = vt;
            #pragma unroll
            for (int i = 0; i < 2; i++) {
                gl_lds16(ksrc + i * 2048 + w * 512 + (lane & 63) * 8, &KV[0][i * 2048 + w * 512]);
                gl_lds16(vsrc + i * 2048 + w * 512 + (lane & 63) * 8, &KV[0][4096 + i * 2048 + w * 512]);
            }
        }

        for (int kb = 0; kb <= qb; kb++) {
            __syncthreads();  // DMA for kb drained; buf[(kb+1)&1] free to overwrite
            if (kb < qb) {
                const int nb = (kb + 1) & 1;
                const u16* ksrc = kt + (size_t)(kb + 1) * 4096;
                const u16* vsrc = vt + (size_t)(kb + 1) * 4096;
                #pragma unroll
                for (int i = 0; i < 2; i++) {
                    gl_lds16(ksrc + i * 2048 + w * 512 + lane * 8, &KV[nb][i * 2048 + w * 512]);
                    gl_lds16(vsrc + i * 2048 + w * 512 + lane * 8, &KV[nb][4096 + i * 2048 + w * 512]);
                }
            }
            const u16* Ksb = &KV[kb & 1][0];
            const u16* Vsb = &KV[kb & 1][4096];

            // S^T = K * Q^T : lane q = l16, key = nt2*16 + quad*4 + r
            f32x4 s[4];
            #pragma unroll
            for (int nt2 = 0; nt2 < 4; nt2++) {
                bf16x8 ak0 = *(const bf16x8*)&Ksb[(nt2 * 16 + l16) * 32 + quad * 8];
                bf16x8 ak1 = *(const bf16x8*)&Ksb[2048 + (nt2 * 16 + l16) * 32 + quad * 8];
                f32x4 z4 = { 0.f, 0.f, 0.f, 0.f };
                s[nt2] = __builtin_amdgcn_mfma_f32_16x16x32_bf16(ak0, bq0, z4, 0, 0, 0);
                s[nt2] = __builtin_amdgcn_mfma_f32_16x16x32_bf16(ak1, bq1, s[nt2], 0, 0, 0);
            }

            if (kb == qb) {  // diagonal: mask key > q
                #pragma unroll
                for (int nt2 = 0; nt2 < 4; nt2++)
                    #pragma unroll
                    for (int r = 0; r < 4; r++)
                        if (nt2 * 16 + quad * 4 + r > q_local) s[nt2][r] = -1e30f;
            }

            // V frags issued before exp so lgkmcnt hides under VALU
            bf16x8 av[8];
            #pragma unroll
            for (int nv = 0; nv < 4; nv++) {
                av[nv * 2]     = *(const bf16x8*)&Vsb[(nv * 16 + l16) * 32 + quad * 8];
                av[nv * 2 + 1] = *(const bf16x8*)&Vsb[2048 + (nv * 16 + l16) * 32 + quad * 8];
            }

            #pragma unroll
            for (int nt2 = 0; nt2 < 4; nt2++)
                #pragma unroll
                for (int r = 0; r < 4; r++) {
                    float pe = __expf(s[nt2][r] - 16.f);
                    s[nt2][r] = pe;
                    lsum += pe;
                }

            bf16x8 bp0 = { f32_to_bf16_trunc(s[0][0]), f32_to_bf16_trunc(s[0][1]),
                           f32_to_bf16_trunc(s[0][2]), f32_to_bf16_trunc(s[0][3]),
                           f32_to_bf16_trunc(s[1][0]), f32_to_bf16_trunc(s[1][1]),
                           f32_to_bf16_trunc(s[1][2]), f32_to_bf16_trunc(s[1][3]) };
            bf16x8 bp1 = { f32_to_bf16_trunc(s[2][0]), f32_to_bf16_trunc(s[2][1]),
                           f32_to_bf16_trunc(s[2][2]), f32_to_bf16_trunc(s[2][3]),
                           f32_to_bf16_trunc(s[3][0]), f32_to_bf16_trunc(s[3][1]),
                           f32_to_bf16_trunc(s[3][2]), f32_to_bf16_trunc(s[3][3]) };
            #pragma unroll
            for (int nv = 0; nv < 4; nv++) {
                o[nv] = __builtin_amdgcn_mfma_f32_16x16x32_bf16(av[nv * 2], bp0, o[nv], 0, 0, 0);
                o[nv] = __builtin_amdgcn_mfma_f32_16x16x32_bf16(av[nv * 2 + 1], bp1, o[nv], 0, 0, 0);
            }
        }

        // epilogue (wave-private scratch, no barrier needed)
        lsum += __shfl_xor(lsum, 16);
        lsum += __shfl_xor(lsum, 32);
        const float inv = 1.f / lsum;
        float* myOw = Ow[w];
        #pragma unroll
        for (int nv = 0; nv < 4; nv++)
            #pragma unroll
            for (int r = 0; r < 4; r++)
                myOw[l16 * 68 + nv * 16 + quad * 4 + r] = o[nv][r] * inv;
        #pragma unroll
        for (int i = 0; i < 4; i++) {
            int row = i * 4 + quad;   // q row within wave's 16
            f32x4 vv = *(const f32x4*)&myOw[row * 68 + l16 * 4];
            u16x4 u = { f32_to_bf16(vv[0]), f32_to_bf16(vv[1]), f32_to_bf16(vv[2]), f32_to_bf16(vv[3]) };
            *(u16x4*)&valsb[(size_t)(qb * 64 + w * 16 + row) * HD + h * 64 + l16 * 4] = u;
        }
    }
}

// ---------------------------------------------------------------------------
// ws layout (u16 idx): qc 0 | kc 4M | vc 8M | wqc 12M | wkc 13M | wvc 14M |
// woc 15M | Qb 16M | KT 20M | VT 24M ; valsb reuses qc; O0/O1 fp32 overlay
// Qb..KT / VT.. (dead after attn). Total 64 MiB.
// ---------------------------------------------------------------------------
extern "C" void kernel_launch(void* const* d_in, const int* in_sizes, int n_in,
                              void* d_out, int out_size, void* d_ws, size_t ws_size,
                              hipStream_t stream) {
    const float* q     = (const float*)d_in[0];
    const float* k     = (const float*)d_in[1];
    const float* v     = (const float*)d_in[2];
    const float* freqs = (const float*)d_in[4];
    const float* wq    = (const float*)d_in[5];
    const float* wk    = (const float*)d_in[6];
    const float* wv    = (const float*)d_in[7];
    const float* wo    = (const float*)d_in[8];

    u16* B = (u16*)d_ws;
    u16* qc  = B;
    u16* kc  = B + (size_t)4194304;
    u16* vc  = B + (size_t)8388608;
    u16* wqc = B + (size_t)12582912;
    u16* wkc = B + (size_t)13631488;
    u16* wvc = B + (size_t)14680064;
    u16* woc = B + (size_t)15728640;
    u16* Qb  = B + (size_t)16777216;
    u16* KT  = B + (size_t)20971520;
    u16* VT  = B + (size_t)25165824;
    u16* valsb = qc;
    float* O0 = (float*)(B + (size_t)16777216);
    float* O1 = (float*)(B + (size_t)25165824);

    CastArgs ca;
    ca.src[0] = q;  ca.dst[0] = qc;  ca.n4[0] = 1048576;
    ca.src[1] = k;  ca.dst[1] = kc;  ca.n4[1] = 1048576;
    ca.src[2] = v;  ca.dst[2] = vc;  ca.n4[2] = 1048576;
    ca.src[3] = wq; ca.dst[3] = wqc; ca.n4[3] = 262144;
    ca.src[4] = wk; ca.dst[4] = wkc; ca.n4[4] = 262144;
    ca.src[5] = wv; ca.dst[5] = wvc; ca.n4[5] = 262144;
    ca.src[6] = wo; ca.dst[6] = woc; ca.n4[6] = 262144;
    cast_kernel<<<dim3(1024, 7), 256, 0, stream>>>(ca);

    gemm_rope<<<dim3(32, 8, 3), 256, 0, stream>>>(
        qc, kc, vc, wqc, wkc, wvc, Qb, KT, VT, freqs);

    attn_kernel<<<dim3(512), 256, 0, stream>>>(Qb, KT, VT, valsb);

    gemm_out<<<dim3(32, 8, 2), 256, 0, stream>>>(valsb, woc, O0, O1);

    add_kernel<<<dim3(4096), 256, 0, stream>>>(O0, O1, (float*)d_out);
}